// Round 5
// baseline (872.515 us; speedup 1.0000x reference)
//
#include <hip/hip_runtime.h>
#include <hip/hip_bf16.h>
#include <cstdint>
#include <cstddef>

#define N_TOK 65536
#define HIDDEN 768
#define NHEAD 12
#define HEADD 64

typedef __bf16 bf16x8 __attribute__((ext_vector_type(8)));
typedef float f32x4 __attribute__((ext_vector_type(4)));

__device__ __forceinline__ float bflo(unsigned int u) {
  return __builtin_bit_cast(float, (unsigned int)(u << 16));
}
__device__ __forceinline__ float bfhi(unsigned int u) {
  return __builtin_bit_cast(float, (unsigned int)(u & 0xffff0000u));
}
__device__ __forceinline__ unsigned short f2bf(float f) {
  unsigned int x = __builtin_bit_cast(unsigned int, f);
  unsigned int r = x + 0x7fffu + ((x >> 16) & 1u);  // RTNE
  return (unsigned short)(r >> 16);
}

__device__ __forceinline__ void gload_lds16(const void* g, void* l) {
  __builtin_amdgcn_global_load_lds(
      (const __attribute__((address_space(1))) void*)g,
      (__attribute__((address_space(3))) void*)l, 16, 0, 0);
}

// Full bank swizzle: physical = logical ^ ((row&7)<<4).  (verified: 0 conflicts)
__device__ __forceinline__ bf16x8 ldsfrag(const char* base, int row, int kb) {
  int L = (row << 7) + kb;        // 128 B rows
  L ^= (row & 7) << 4;
  return *(const bf16x8*)(base + L);
}

// ------- fused weight converts + bias concat (one launch) -------
__global__ void cvtw_kernel(const float* __restrict__ Wq, const float* __restrict__ Wk,
                            const float* __restrict__ Wv, const float* __restrict__ Wo,
                            const float* __restrict__ bq, const float* __restrict__ bk,
                            const float* __restrict__ bv,
                            unsigned short* __restrict__ wqkv,
                            unsigned short* __restrict__ wo_bf,
                            float* __restrict__ bqkv) {
  const int bid = blockIdx.x;
  if (bid < 2304) {
    const int mat = bid / 576;
    const int idx = (bid - mat * 576) * 256 + threadIdx.x;
    const float* src = mat == 0 ? Wq : mat == 1 ? Wk : mat == 2 ? Wv : Wo;
    unsigned short* dst = (mat == 3) ? wo_bf : wqkv + mat * (HIDDEN * HIDDEN);
    float4 v = ((const float4*)src)[idx];
    ushort4 o;
    o.x = f2bf(v.x); o.y = f2bf(v.y); o.z = f2bf(v.z); o.w = f2bf(v.w);
    ((ushort4*)dst)[idx] = o;
  } else {
    const int i = (bid - 2304) * 256 + threadIdx.x;  // float4 index over 576
    if (i < 576) {
      const float* src = i < 192 ? bq : i < 384 ? bk : bv;
      const int off = i < 192 ? i : i < 384 ? i - 192 : i - 384;
      ((float4*)bqkv)[i] = ((const float4*)src)[off];
    }
  }
}

// ---------- persistent per-M-panel GEMM phase: C[panel] = A[panel] @ B^T + bias ----------
// A: [.][768] bf16 (only rows mb*256..+255 touched), B: [NBLK*256][768] bf16.
// Walks NBLK 256-col output tiles with a single flattened, double-buffered,
// single-barrier-per-phase pipeline (prologue paid once).
template <int NBLK, int F32OUT>
__device__ __forceinline__ void gemm_panel(
    const unsigned short* __restrict__ A,
    const unsigned short* __restrict__ B,
    const float* __restrict__ bias,
    void* __restrict__ C, int ldc,
    int mb, char* lds, int tid) {
  constexpr int K = 768;
  constexpr int NT = K / 64;        // 12
  constexpr int G = NBLK * NT;
  const int lane = tid & 63;
  const int wave = tid >> 6;
  const int wr = wave >> 2;   // 0..1
  const int wc = wave & 3;    // 0..3
  const int brow = mb << 8;

  // staging: linear LDS dest (tid*16), inverse-swizzled global source
  const int Ld = tid * 16;
  const int Ls = Ld ^ (((tid >> 3) & 7) << 4);
  const int sr = Ls >> 7;           // source row within 64-row chunk
  const int sc = (Ls & 127) >> 1;   // source col element

  const unsigned short* Abase = A + (size_t)(brow + sr) * K + sc;
  const unsigned short* Bbase = B + (size_t)sr * K + sc;

#define STG_A(bufbase, half, kt)                                        \
  do {                                                                  \
    const unsigned short* _s = Abase + ((half) * 128) * K + (kt) * 64;  \
    char* _d = lds + (bufbase) + ((half) << 14) + Ld;                   \
    gload_lds16(_s, _d);                                                \
    gload_lds16(_s + 64 * K, _d + 8192);                                \
  } while (0)
#define STG_B(bufbase, nbx, half, kt)                                   \
  do {                                                                  \
    const unsigned short* _s =                                          \
        Bbase + (size_t)((nbx) * 256 + (half) * 128) * K + (kt) * 64;   \
    char* _d = lds + (bufbase) + 32768 + ((half) << 14) + Ld;           \
    gload_lds16(_s, _d);                                                \
    gload_lds16(_s + 64 * K, _d + 8192);                                \
  } while (0)

  f32x4 acc[8][4];
#pragma unroll
  for (int m = 0; m < 8; ++m)
#pragma unroll
    for (int n = 0; n < 4; ++n) acc[m][n] = (f32x4){0.f, 0.f, 0.f, 0.f};

  const int arow = wr * 128 + (lane & 15);
  const int nrow = wc * 64 + (lane & 15);
  const int kpart = (lane >> 4) * 16;

  // ---- prologue: stage tile g=0, drain, barrier (paid ONCE per phase) ----
  STG_A(0, 0, 0);
  STG_A(0, 1, 0);
  STG_B(0, 0, 0, 0);
  STG_B(0, 0, 1, 0);
  asm volatile("s_waitcnt vmcnt(0)" ::: "memory");
  __builtin_amdgcn_s_barrier();

  int t = 0, nb = 0;
  for (int g = 0; g < G; ++g) {
    const int cur = g & 1;
    const char* la = lds + cur * 65536;
    const char* lb = la + 32768;
    const int obuf = (cur ^ 1) * 65536;
    const int t1 = (t == NT - 1) ? 0 : t + 1;
    const int nb1 = (t == NT - 1) ? nb + 1 : nb;
    const bool more = (g + 1 < G);

    bf16x8 aLo[8], aHi[8], bLo[4], bHi[4];

    // -------- PH1: read aLo(8)+bLo(4); stage A(g+1); MFMA Q(lo,lo) --------
#pragma unroll
    for (int m = 0; m < 4; ++m)
#pragma unroll
      for (int kk = 0; kk < 2; ++kk)
        aLo[m * 2 + kk] = ldsfrag(la, arow + m * 16, kk * 64 + kpart);
#pragma unroll
    for (int n = 0; n < 2; ++n)
#pragma unroll
      for (int kk = 0; kk < 2; ++kk)
        bLo[n * 2 + kk] = ldsfrag(lb, nrow + n * 16, kk * 64 + kpart);
    if (more) {
      STG_A(obuf, 0, t1);
      STG_A(obuf, 1, t1);
    }
    __builtin_amdgcn_s_barrier();
    asm volatile("s_waitcnt lgkmcnt(0)" ::: "memory");
    __builtin_amdgcn_s_setprio(1);
#pragma unroll
    for (int m = 0; m < 4; ++m)
#pragma unroll
      for (int n = 0; n < 2; ++n)
#pragma unroll
        for (int kk = 0; kk < 2; ++kk)
          acc[m][n] = __builtin_amdgcn_mfma_f32_16x16x32_bf16(
              aLo[m * 2 + kk], bLo[n * 2 + kk], acc[m][n], 0, 0, 0);
    __builtin_amdgcn_s_setprio(0);

    // -------- PH2: read aHi(8); stage B(g+1); MFMA Q(hi,lo) --------
#pragma unroll
    for (int m = 0; m < 4; ++m)
#pragma unroll
      for (int kk = 0; kk < 2; ++kk)
        aHi[m * 2 + kk] = ldsfrag(la, arow + 64 + m * 16, kk * 64 + kpart);
    if (more) {
      STG_B(obuf, nb1, 0, t1);
      STG_B(obuf, nb1, 1, t1);
    }
    __builtin_amdgcn_s_barrier();
    asm volatile("s_waitcnt lgkmcnt(0)" ::: "memory");
    __builtin_amdgcn_s_setprio(1);
#pragma unroll
    for (int m = 0; m < 4; ++m)
#pragma unroll
      for (int n = 0; n < 2; ++n)
#pragma unroll
        for (int kk = 0; kk < 2; ++kk)
          acc[4 + m][n] = __builtin_amdgcn_mfma_f32_16x16x32_bf16(
              aHi[m * 2 + kk], bLo[n * 2 + kk], acc[4 + m][n], 0, 0, 0);
    __builtin_amdgcn_s_setprio(0);

    // -------- PH3: read bHi(4); MFMA Q(hi,hi) --------
#pragma unroll
    for (int n = 0; n < 2; ++n)
#pragma unroll
      for (int kk = 0; kk < 2; ++kk)
        bHi[n * 2 + kk] = ldsfrag(lb, nrow + 32 + n * 16, kk * 64 + kpart);
    __builtin_amdgcn_s_barrier();
    asm volatile("s_waitcnt lgkmcnt(0)" ::: "memory");
    __builtin_amdgcn_s_setprio(1);
#pragma unroll
    for (int m = 0; m < 4; ++m)
#pragma unroll
      for (int n = 0; n < 2; ++n)
#pragma unroll
        for (int kk = 0; kk < 2; ++kk)
          acc[4 + m][n + 2] = __builtin_amdgcn_mfma_f32_16x16x32_bf16(
              aHi[m * 2 + kk], bHi[n * 2 + kk], acc[4 + m][n + 2], 0, 0, 0);
    __builtin_amdgcn_s_setprio(0);

    // -------- PH4: vmcnt drain (g+1 fully staged >=2 phases ago); MFMA Q(lo,hi) --
    asm volatile("s_waitcnt vmcnt(0)" ::: "memory");
    __builtin_amdgcn_s_barrier();
    __builtin_amdgcn_s_setprio(1);
#pragma unroll
    for (int m = 0; m < 4; ++m)
#pragma unroll
      for (int n = 0; n < 2; ++n)
#pragma unroll
        for (int kk = 0; kk < 2; ++kk)
          acc[m][n + 2] = __builtin_amdgcn_mfma_f32_16x16x32_bf16(
              aLo[m * 2 + kk], bHi[n * 2 + kk], acc[m][n + 2], 0, 0, 0);
    __builtin_amdgcn_s_setprio(0);

    // -------- per-output-tile epilogue (stores overlap next tile's phases) --
    if (t == NT - 1) {
      const int crow0 = brow + wr * 128 + (lane >> 4) * 4;
      const int ccol0 = nb * 256 + wc * 64 + (lane & 15);
#pragma unroll
      for (int m = 0; m < 8; ++m) {
#pragma unroll
        for (int n = 0; n < 4; ++n) {
          const int col = ccol0 + n * 16;
          const float bv = bias[col];
#pragma unroll
          for (int r = 0; r < 4; ++r) {
            const int row = crow0 + m * 16 + r;
            const float v = acc[m][n][r] + bv;
            if (F32OUT)
              ((float*)C)[(size_t)row * ldc + col] = v;
            else
              ((unsigned short*)C)[(size_t)row * ldc + col] = f2bf(v);
          }
          acc[m][n] = (f32x4){0.f, 0.f, 0.f, 0.f};
        }
      }
      t = 0;
      ++nb;
    } else {
      ++t;
    }
  }
#undef STG_A
#undef STG_B
}

// ---------------- fused persistent kernel: one block = 256 tokens ----------------
// Phase A: convert own x panel f32->bf16.  Phase B: QKV GEMM (9 tiles).
// Phase C: per-token 12x12 attention.     Phase D: output GEMM (3 tiles).
// All intermediates are block-private rows -> L2-local.
__global__ __launch_bounds__(512, 2)
void fused_kernel(const float* __restrict__ x,
                  const unsigned short* __restrict__ wqkv,
                  const unsigned short* __restrict__ wo_bf,
                  const float* __restrict__ bqkv,
                  const float* __restrict__ bo,
                  unsigned short* __restrict__ x_bf,
                  unsigned short* __restrict__ qkv,
                  unsigned short* __restrict__ ctx,
                  float* __restrict__ out) {
  __shared__ __align__(16) char lds[131072];
  const int tid = threadIdx.x;
  const int mb = blockIdx.x;

  // ---- Phase A: convert own 256x768 panel ----
  {
    const float4* src = (const float4*)(x + (size_t)mb * 196608);
    ushort4* dst = (ushort4*)(x_bf + (size_t)mb * 196608);
#pragma unroll 4
    for (int i = 0; i < 96; ++i) {
      const int idx = i * 512 + tid;
      float4 v = src[idx];
      ushort4 o;
      o.x = f2bf(v.x); o.y = f2bf(v.y); o.z = f2bf(v.z); o.w = f2bf(v.w);
      dst[idx] = o;
    }
  }
  asm volatile("s_waitcnt vmcnt(0)" ::: "memory");
  __syncthreads();

  // ---- Phase B: QKV GEMM: panel @ wqkv^T + bqkv -> qkv (bf16) ----
  gemm_panel<9, 0>(x_bf, wqkv, bqkv, qkv, 2304, mb, lds, tid);
  asm volatile("s_waitcnt vmcnt(0)" ::: "memory");
  __syncthreads();

  // ---- Phase C: per-token 12x12 attention -> ctx (bf16) ----
#pragma unroll 1
  for (int i = 0; i < 6; ++i) {
    const int p = i * 512 + tid;          // 0..3071 = 256 tokens * 12 heads
    const int tok = p / 12;
    const int h = p - tok * 12;
    const size_t grow = (size_t)(mb * 256 + tok);
    const unsigned short* row = qkv + grow * 2304;
    const unsigned short* qp = row + h * 64;
    const unsigned short* kp = row + 768;

    float s[12];
#pragma unroll
    for (int g = 0; g < 12; ++g) s[g] = 0.f;

#pragma unroll 1
    for (int c = 0; c < 8; ++c) {
      const uint4 qc = *(const uint4*)(qp + c * 8);
      const unsigned int qw[4] = {qc.x, qc.y, qc.z, qc.w};
#pragma unroll
      for (int j = 0; j < 8; ++j) {
        const float qd = (j & 1) ? bfhi(qw[j >> 1]) : bflo(qw[j >> 1]);
        const unsigned short* kd = kp + (c * 8 + j) * 12;
        const uint2 k0 = *(const uint2*)(kd);
        const uint2 k1 = *(const uint2*)(kd + 4);
        const uint2 k2 = *(const uint2*)(kd + 8);
        s[0] += qd * bflo(k0.x);  s[1] += qd * bfhi(k0.x);
        s[2] += qd * bflo(k0.y);  s[3] += qd * bfhi(k0.y);
        s[4] += qd * bflo(k1.x);  s[5] += qd * bfhi(k1.x);
        s[6] += qd * bflo(k1.y);  s[7] += qd * bfhi(k1.y);
        s[8] += qd * bflo(k2.x);  s[9] += qd * bfhi(k2.x);
        s[10] += qd * bflo(k2.y); s[11] += qd * bfhi(k2.y);
      }
    }

    float mx = s[0];
#pragma unroll
    for (int g = 1; g < 12; ++g) mx = fmaxf(mx, s[g]);
    float pr[12];
    float sum = 0.f;
#pragma unroll
    for (int g = 0; g < 12; ++g) {
      pr[g] = __expf((s[g] - mx) * 0.125f);
      sum += pr[g];
    }
    const float inv = 1.0f / sum;
#pragma unroll
    for (int g = 0; g < 12; ++g) pr[g] *= inv;

    const unsigned short* vp = row + 1536;
    unsigned short* op = ctx + grow * 768 + h * 64;
#pragma unroll 1
    for (int c = 0; c < 8; ++c) {
      float o[8];
#pragma unroll
      for (int k = 0; k < 8; ++k) o[k] = 0.f;
#pragma unroll
      for (int g = 0; g < 12; ++g) {
        const uint4 vv = *(const uint4*)(vp + g * 64 + c * 8);
        const unsigned int vw[4] = {vv.x, vv.y, vv.z, vv.w};
#pragma unroll
        for (int k = 0; k < 4; ++k) {
          o[2 * k] += pr[g] * bflo(vw[k]);
          o[2 * k + 1] += pr[g] * bfhi(vw[k]);
        }
      }
      uint4 w;
      w.x = (unsigned int)f2bf(o[0]) | ((unsigned int)f2bf(o[1]) << 16);
      w.y = (unsigned int)f2bf(o[2]) | ((unsigned int)f2bf(o[3]) << 16);
      w.z = (unsigned int)f2bf(o[4]) | ((unsigned int)f2bf(o[5]) << 16);
      w.w = (unsigned int)f2bf(o[6]) | ((unsigned int)f2bf(o[7]) << 16);
      *(uint4*)(op + c * 8) = w;
    }
  }
  asm volatile("s_waitcnt vmcnt(0)" ::: "memory");
  __syncthreads();

  // ---- Phase D: output GEMM: ctx @ wo^T + bo -> out (f32) ----
  gemm_panel<3, 1>(ctx, wo_bf, bo, out, 768, mb, lds, tid);
}

extern "C" void kernel_launch(void* const* d_in, const int* in_sizes, int n_in,
                              void* d_out, int out_size, void* d_ws, size_t ws_size,
                              hipStream_t stream) {
  const float* x = (const float*)d_in[0];
  const float* Wq = (const float*)d_in[1];
  const float* bq = (const float*)d_in[2];
  const float* Wk = (const float*)d_in[3];
  const float* bk = (const float*)d_in[4];
  const float* Wv = (const float*)d_in[5];
  const float* bv = (const float*)d_in[6];
  const float* Wo = (const float*)d_in[7];
  const float* bo = (const float*)d_in[8];
  float* out = (float*)d_out;

  char* ws = (char*)d_ws;
  unsigned short* x_bf = (unsigned short*)ws;
  unsigned short* ctx = (unsigned short*)ws;  // alias: rows are block-private,
                                              // x_bf row dead before ctx write
  unsigned short* qkv = (unsigned short*)(ws + 100663296u);
  unsigned short* wqkv = (unsigned short*)(ws + 402653184u);
  unsigned short* wo_bf = (unsigned short*)(ws + 406192128u);
  float* bqkv = (float*)(ws + 407371776u);

  cvtw_kernel<<<2307, 256, 0, stream>>>(Wq, Wk, Wv, Wo, bq, bk, bv,
                                        wqkv, wo_bf, bqkv);

  fused_kernel<<<256, 512, 0, stream>>>(x, wqkv, wo_bf, bqkv, bo,
                                        x_bf, qkv, ctx, out);
}

// Round 6
// 688.328 us; speedup vs baseline: 1.2676x; 1.2676x over previous
//
#include <hip/hip_runtime.h>
#include <hip/hip_bf16.h>
#include <cstdint>
#include <cstddef>

#define N_TOK 65536
#define HIDDEN 768
#define NHEAD 12
#define HEADD 64

typedef __bf16 bf16x8 __attribute__((ext_vector_type(8)));
typedef float f32x16 __attribute__((ext_vector_type(16)));

__device__ __forceinline__ float bflo(unsigned int u) {
  return __builtin_bit_cast(float, (unsigned int)(u << 16));
}
__device__ __forceinline__ float bfhi(unsigned int u) {
  return __builtin_bit_cast(float, (unsigned int)(u & 0xffff0000u));
}
__device__ __forceinline__ unsigned short f2bf(float f) {
  unsigned int x = __builtin_bit_cast(unsigned int, f);
  unsigned int r = x + 0x7fffu + ((x >> 16) & 1u);  // RTNE
  return (unsigned short)(r >> 16);
}

__device__ __forceinline__ void gload_lds16(const void* g, void* l) {
  __builtin_amdgcn_global_load_lds(
      (const __attribute__((address_space(1))) void*)g,
      (__attribute__((address_space(3))) void*)l, 16, 0, 0);
}

// ---------------- f32 -> bf16 convert of x (vectorized) ----------------
__global__ void cvt_kernel(const float* __restrict__ in,
                           unsigned short* __restrict__ out, int n4) {
  int i = blockIdx.x * blockDim.x + threadIdx.x;
  if (i >= n4) return;
  float4 v = ((const float4*)in)[i];
  ushort4 o;
  o.x = f2bf(v.x); o.y = f2bf(v.y); o.z = f2bf(v.z); o.w = f2bf(v.w);
  ((ushort4*)out)[i] = o;
}

// ------- fused weight converts + bias concat (one launch) -------
__global__ void cvtw_kernel(const float* __restrict__ Wq, const float* __restrict__ Wk,
                            const float* __restrict__ Wv, const float* __restrict__ Wo,
                            const float* __restrict__ bq, const float* __restrict__ bk,
                            const float* __restrict__ bv,
                            unsigned short* __restrict__ wqkv,
                            unsigned short* __restrict__ wo_bf,
                            float* __restrict__ bqkv) {
  const int bid = blockIdx.x;
  if (bid < 2304) {
    const int mat = bid / 576;
    const int idx = (bid - mat * 576) * 256 + threadIdx.x;
    const float* src = mat == 0 ? Wq : mat == 1 ? Wk : mat == 2 ? Wv : Wo;
    unsigned short* dst = (mat == 3) ? wo_bf : wqkv + mat * (HIDDEN * HIDDEN);
    float4 v = ((const float4*)src)[idx];
    ushort4 o;
    o.x = f2bf(v.x); o.y = f2bf(v.y); o.z = f2bf(v.z); o.w = f2bf(v.w);
    ((ushort4*)dst)[idx] = o;
  } else {
    const int i = (bid - 2304) * 256 + threadIdx.x;
    if (i < 576) {
      const float* src = i < 192 ? bq : i < 384 ? bk : bv;
      const int off = i < 192 ? i : i < 384 ? i - 192 : i - 384;
      ((float4*)bqkv)[i] = ((const float4*)src)[off];
    }
  }
}

// ------------- 256x256 bf16 GEMM, C = A @ B^T + bias -------------
// 32x32x16 MFMA, BK=64, 8 waves (2M x 4N), per-wave 128x64 output,
// double-buffered LDS + (row&7)<<4 XOR swizzle (0 conflicts, verified),
// single barrier per phase, t+2 prefetch with counted vmcnt(8).
// ds_read addresses: swizzle folded into per-thread constants -> base + imm.
template <int F32OUT>
__global__ __launch_bounds__(512, 2)
void gemm256(const unsigned short* __restrict__ A,
             const unsigned short* __restrict__ B,
             const float* __restrict__ bias,
             void* __restrict__ C, int K, int NBLK, int ldc) {
  __shared__ __align__(16) char lds[131072];
  const int tid = threadIdx.x;
  const int lane = tid & 63;
  const int wave = tid >> 6;
  const int wr = wave >> 2;   // 0..1
  const int wc = wave & 3;    // 0..3

  // XCD-aware bijective swizzle (grid % 8 == 0 by construction)
  const int nwg = gridDim.x;
  const int bid = blockIdx.x;
  const int wg = (bid & 7) * (nwg >> 3) + (bid >> 3);
  const int mb = wg / NBLK;
  const int nb = wg - mb * NBLK;
  const int brow = mb << 8;
  const int bcol = nb << 8;

  // staging: linear LDS dest (tid*16), inverse-swizzled global source
  const int Ld = tid * 16;
  const int Ls = Ld ^ (((tid >> 3) & 7) << 4);
  const int sr = Ls >> 7;
  const int sc = (Ls & 127) >> 1;

  const int NT = K >> 6;

#define STAGE(Mat, panelRow, bufbase, half, matoff, kt)                         \
  do {                                                                          \
    const unsigned short* _s =                                                  \
        (Mat) + (size_t)((panelRow) + (half) * 128 + sr) * K + ((kt) << 6) + sc;\
    char* _d = (char*)lds + (bufbase) + (matoff) + ((half) << 14) + Ld;         \
    gload_lds16(_s, _d);                                                        \
    gload_lds16(_s + ((size_t)K << 6), _d + 8192);                              \
  } while (0)

  f32x16 acc[4][2];
#pragma unroll
  for (int m = 0; m < 4; ++m)
#pragma unroll
    for (int n = 0; n < 2; ++n)
#pragma unroll
      for (int r = 0; r < 16; ++r) acc[m][n][r] = 0.f;

  // fragment addressing (32x32x16): A row = lane&31, k = (lane>>5)*8 + j
  const int lane31 = lane & 31;
  const int arow = wr * 128 + lane31;   // A-tile row for this lane
  const int brn = wc * 64 + lane31;     // B-tile row (C col) for this lane
  const int kb16 = (lane >> 5) * 16;    // byte offset of k-slice
  int akoff[4], bkoff[4];               // swizzle folded per k-step
#pragma unroll
  for (int ks = 0; ks < 4; ++ks) {
    akoff[ks] = (ks * 32 + kb16) ^ ((arow & 7) << 4);
    bkoff[ks] = (ks * 32 + kb16) ^ ((brn & 7) << 4);
  }

  // ---- prologue: stage tiles 0 and 1 fully, wait tile 0 (vmcnt(8)) ----
  STAGE(A, brow, 0, 0, 0, 0);
  STAGE(A, brow, 0, 1, 0, 0);
  STAGE(B, bcol, 0, 0, 32768, 0);
  STAGE(B, bcol, 0, 1, 32768, 0);
  STAGE(A, brow, 65536, 0, 0, 1);
  STAGE(A, brow, 65536, 1, 0, 1);
  STAGE(B, bcol, 65536, 0, 32768, 1);
  STAGE(B, bcol, 65536, 1, 32768, 1);
  asm volatile("s_waitcnt vmcnt(8)" ::: "memory");
  __builtin_amdgcn_s_barrier();

  for (int t = 0; t < NT; ++t) {
    const int cur = t & 1;
    const char* la = lds + cur * 65536;
    const char* lb = la + 32768;
    const int sbuf = cur * 65536;  // tile t+2 goes where tile t was
    const char* aB = la + arow * 128;
    const char* bB = lb + brn * 128;
    const bool pf = (t + 2 < NT);

    bf16x8 aL[2][4], aH[2][4], b0[4], b1[4];

    // -------- PH1: read aL(8)+b0(4); MFMA m01 x n0 --------
#pragma unroll
    for (int mi = 0; mi < 2; ++mi)
#pragma unroll
      for (int ks = 0; ks < 4; ++ks)
        aL[mi][ks] = *(const bf16x8*)(aB + mi * 4096 + akoff[ks]);
#pragma unroll
    for (int ks = 0; ks < 4; ++ks)
      b0[ks] = *(const bf16x8*)(bB + bkoff[ks]);
    __builtin_amdgcn_s_barrier();
    asm volatile("s_waitcnt lgkmcnt(0)" ::: "memory");
    __builtin_amdgcn_s_setprio(1);
#pragma unroll
    for (int mi = 0; mi < 2; ++mi)
#pragma unroll
      for (int ks = 0; ks < 4; ++ks)
        acc[mi][0] = __builtin_amdgcn_mfma_f32_32x32x16_bf16(
            aL[mi][ks], b0[ks], acc[mi][0], 0, 0, 0);
    __builtin_amdgcn_s_setprio(0);

    // -------- PH2: read aH(8); MFMA m23 x n0 --------
#pragma unroll
    for (int mi = 0; mi < 2; ++mi)
#pragma unroll
      for (int ks = 0; ks < 4; ++ks)
        aH[mi][ks] = *(const bf16x8*)(aB + (2 + mi) * 4096 + akoff[ks]);
    __builtin_amdgcn_s_barrier();
    asm volatile("s_waitcnt lgkmcnt(0)" ::: "memory");
    __builtin_amdgcn_s_setprio(1);
#pragma unroll
    for (int mi = 0; mi < 2; ++mi)
#pragma unroll
      for (int ks = 0; ks < 4; ++ks)
        acc[2 + mi][0] = __builtin_amdgcn_mfma_f32_32x32x16_bf16(
            aH[mi][ks], b0[ks], acc[2 + mi][0], 0, 0, 0);
    __builtin_amdgcn_s_setprio(0);

    // -------- PH3: read b1(4); stage A(t+2); MFMA m23 x n1 --------
#pragma unroll
    for (int ks = 0; ks < 4; ++ks)
      b1[ks] = *(const bf16x8*)(bB + 4096 + bkoff[ks]);
    if (pf) {
      STAGE(A, brow, sbuf, 0, 0, t + 2);
      STAGE(A, brow, sbuf, 1, 0, t + 2);
    }
    __builtin_amdgcn_s_barrier();
    asm volatile("s_waitcnt lgkmcnt(0)" ::: "memory");
    __builtin_amdgcn_s_setprio(1);
#pragma unroll
    for (int mi = 0; mi < 2; ++mi)
#pragma unroll
      for (int ks = 0; ks < 4; ++ks)
        acc[2 + mi][1] = __builtin_amdgcn_mfma_f32_32x32x16_bf16(
            aH[mi][ks], b1[ks], acc[2 + mi][1], 0, 0, 0);
    __builtin_amdgcn_s_setprio(0);

    // -------- PH4: stage B(t+2); counted vmcnt; MFMA m01 x n1 --------
    if (pf) {
      STAGE(B, bcol, sbuf, 0, 32768, t + 2);
      STAGE(B, bcol, sbuf, 1, 32768, t + 2);
      asm volatile("s_waitcnt vmcnt(8)" ::: "memory");  // exactly t+2 in flight
    } else {
      asm volatile("s_waitcnt vmcnt(0)" ::: "memory");
    }
    __builtin_amdgcn_s_barrier();
    __builtin_amdgcn_s_setprio(1);
#pragma unroll
    for (int mi = 0; mi < 2; ++mi)
#pragma unroll
      for (int ks = 0; ks < 4; ++ks)
        acc[mi][1] = __builtin_amdgcn_mfma_f32_32x32x16_bf16(
            aL[mi][ks], b1[ks], acc[mi][1], 0, 0, 0);
    __builtin_amdgcn_s_setprio(0);
  }
#undef STAGE

  // ---------------- epilogue (32x32 C layout) ----------------
  // col = lane&31; row = (r&3) + 8*(r>>2) + 4*(lane>>5)
  const int crow0 = brow + wr * 128 + 4 * (lane >> 5);
  const int ccol0 = bcol + wc * 64 + lane31;
#pragma unroll
  for (int m = 0; m < 4; ++m) {
#pragma unroll
    for (int n = 0; n < 2; ++n) {
      const int col = ccol0 + n * 32;
      const float bv = bias[col];
#pragma unroll
      for (int r = 0; r < 16; ++r) {
        const int row = crow0 + m * 32 + (r & 3) + 8 * (r >> 2);
        const float v = acc[m][n][r] + bv;
        if (F32OUT)
          ((float*)C)[(size_t)row * ldc + col] = v;
        else
          ((unsigned short*)C)[(size_t)row * ldc + col] = f2bf(v);
      }
    }
  }
}

// ---------------- per-token 12x12 attention -----------------------
__global__ void attn_kernel(const unsigned short* __restrict__ qkv,
                            unsigned short* __restrict__ ctx) {
  const int gtid = blockIdx.x * blockDim.x + threadIdx.x;
  const int t = gtid / 12;
  const int h = gtid - t * 12;
  if (t >= N_TOK) return;

  const unsigned short* row = qkv + (size_t)t * 2304;
  const unsigned short* qp = row + h * 64;
  const unsigned short* kp = row + 768;

  float s[12];
#pragma unroll
  for (int g = 0; g < 12; ++g) s[g] = 0.f;

  for (int c = 0; c < 8; ++c) {
    const uint4 qc = *(const uint4*)(qp + c * 8);
    const unsigned int qw[4] = {qc.x, qc.y, qc.z, qc.w};
#pragma unroll
    for (int j = 0; j < 8; ++j) {
      const float qd = (j & 1) ? bfhi(qw[j >> 1]) : bflo(qw[j >> 1]);
      const unsigned short* kd = kp + (c * 8 + j) * 12;
      const uint2 k0 = *(const uint2*)(kd);
      const uint2 k1 = *(const uint2*)(kd + 4);
      const uint2 k2 = *(const uint2*)(kd + 8);
      s[0] += qd * bflo(k0.x);  s[1] += qd * bfhi(k0.x);
      s[2] += qd * bflo(k0.y);  s[3] += qd * bfhi(k0.y);
      s[4] += qd * bflo(k1.x);  s[5] += qd * bfhi(k1.x);
      s[6] += qd * bflo(k1.y);  s[7] += qd * bfhi(k1.y);
      s[8] += qd * bflo(k2.x);  s[9] += qd * bfhi(k2.x);
      s[10] += qd * bflo(k2.y); s[11] += qd * bfhi(k2.y);
    }
  }

  float mx = s[0];
#pragma unroll
  for (int g = 1; g < 12; ++g) mx = fmaxf(mx, s[g]);
  float p[12];
  float sum = 0.f;
#pragma unroll
  for (int g = 0; g < 12; ++g) {
    p[g] = __expf((s[g] - mx) * 0.125f);
    sum += p[g];
  }
  const float inv = 1.0f / sum;
#pragma unroll
  for (int g = 0; g < 12; ++g) p[g] *= inv;

  const unsigned short* vp = row + 1536;
  unsigned short* op = ctx + (size_t)t * 768 + h * 64;
  for (int c = 0; c < 8; ++c) {
    float o[8];
#pragma unroll
    for (int k = 0; k < 8; ++k) o[k] = 0.f;
#pragma unroll
    for (int g = 0; g < 12; ++g) {
      const uint4 vv = *(const uint4*)(vp + g * 64 + c * 8);
      const unsigned int vw[4] = {vv.x, vv.y, vv.z, vv.w};
#pragma unroll
      for (int k = 0; k < 4; ++k) {
        o[2 * k] += p[g] * bflo(vw[k]);
        o[2 * k + 1] += p[g] * bfhi(vw[k]);
      }
    }
    uint4 w;
    w.x = (unsigned int)f2bf(o[0]) | ((unsigned int)f2bf(o[1]) << 16);
    w.y = (unsigned int)f2bf(o[2]) | ((unsigned int)f2bf(o[3]) << 16);
    w.z = (unsigned int)f2bf(o[4]) | ((unsigned int)f2bf(o[5]) << 16);
    w.w = (unsigned int)f2bf(o[6]) | ((unsigned int)f2bf(o[7]) << 16);
    *(uint4*)(op + c * 8) = w;
  }
}

extern "C" void kernel_launch(void* const* d_in, const int* in_sizes, int n_in,
                              void* d_out, int out_size, void* d_ws, size_t ws_size,
                              hipStream_t stream) {
  const float* x = (const float*)d_in[0];
  const float* Wq = (const float*)d_in[1];
  const float* bq = (const float*)d_in[2];
  const float* Wk = (const float*)d_in[3];
  const float* bk = (const float*)d_in[4];
  const float* Wv = (const float*)d_in[5];
  const float* bv = (const float*)d_in[6];
  const float* Wo = (const float*)d_in[7];
  const float* bo = (const float*)d_in[8];
  float* out = (float*)d_out;

  char* ws = (char*)d_ws;
  unsigned short* x_bf = (unsigned short*)ws;
  unsigned short* ctx = (unsigned short*)ws;  // alias: x_bf dead before attn
  unsigned short* qkv = (unsigned short*)(ws + 100663296u);
  unsigned short* wqkv = (unsigned short*)(ws + 402653184u);
  unsigned short* wo_bf = (unsigned short*)(ws + 406192128u);
  float* bqkv = (float*)(ws + 407371776u);

  const int n4x = N_TOK * HIDDEN / 4;
  cvt_kernel<<<n4x / 256, 256, 0, stream>>>(x, x_bf, n4x);
  cvtw_kernel<<<2307, 256, 0, stream>>>(Wq, Wk, Wv, Wo, bq, bk, bv,
                                        wqkv, wo_bf, bqkv);

  // QKV GEMM: [65536 x 768] @ [2304 x 768]^T + bqkv -> qkv bf16
  gemm256<0><<<(N_TOK / 256) * (2304 / 256), 512, 0, stream>>>(
      x_bf, wqkv, bqkv, qkv, HIDDEN, 2304 / 256, 2304);

  // per-token attention -> ctx bf16
  attn_kernel<<<(N_TOK * NHEAD) / 256, 256, 0, stream>>>(qkv, ctx);

  // output projection: [65536 x 768] @ [768 x 768]^T + bo -> out f32
  gemm256<1><<<(N_TOK / 256) * (HIDDEN / 256), 512, 0, stream>>>(
      ctx, wo_bf, bo, out, HIDDEN, HIDDEN / 256, HIDDEN);
}